// Round 13
// baseline (128.146 us; speedup 1.0000x reference)
//
#include <hip/hip_runtime.h>
#include <math.h>

#define Wd 256
#define Hd 256
#define KW 11
#define OUT_R 26              // output rows per block; stream 36 = 3 chunks of 12
#define RING 12               // ring size 12: slot=(2*jp+c)%12, chunk-independent
#define BLOCK 256

typedef float v2f __attribute__((ext_vector_type(2)));

__device__ __forceinline__ float rfl(float v) {
    return __int_as_float(__builtin_amdgcn_readfirstlane(__float_as_int(v)));
}

// lgkmcnt-only barrier (R2/R5): LDS handoff without draining global prefetch.
__device__ __forceinline__ void barrier_lds_only() {
    asm volatile("s_waitcnt lgkmcnt(0)\n\ts_barrier" ::: "memory");
}

// R13: R5 kernel (best measured: 42.2us dispatch, dur_us 119.9) + s_setprio
// around the emit computation.
//
// Ledger (~42us invariant): barrier flavor (R2), barrier COUNT (R12: 6 vs 13
// -- neutral), residency (R4), prefetch depth (R5 -4%), skew (R6), step size
// & LDS traffic (R7: 1.56x fewer reads -- neutral), bank conflicts (43K vs
// 3M -- no effect), memory residency (L3==HBM), instruction packing (R9:
// fewer inst = SLOWER), wave privatization (R10), atomics (R11). Surviving
// model: duration = VALU-busy-time (~18us, near compute floor) x ~2.4
// latency-gap multiplier at ~3-4 resident block-streams/CU.
//
// T5 mechanism match: co-resident blocks are mutually OUT of phase (the
// attn case where setprio measured +4-7%, m191). Raising priority during
// the compute phase biases the CU scheduler toward FMA-issuing waves over
// load-issuing/barrier-waiting waves of other blocks.
__global__ __launch_bounds__(BLOCK, 4) void ssim_pair_kernel(
    const float* __restrict__ img1, const float* __restrict__ img2,
    const float* __restrict__ window, float* __restrict__ out, float scale)
{
    __shared__ __align__(16) float4 rbE[2][2][136];
    __shared__ __align__(16) float4 rbO[2][2][136];   // 17.4 KB
    __shared__ float red[BLOCK / 64];

    const float C1 = 1e-4f, C2 = 9e-4f;
    const int t = threadIdx.x;
    const int band = blockIdx.x;     // 0..9 (band 9 partial: 22 rows)
    const int plane = blockIdx.y;    // 0..143
    const float* __restrict__ p1 = img1 + (size_t)plane * (Hd * Wd);
    const float* __restrict__ p2 = img2 + (size_t)plane * (Hd * Wd);

    // Separable 1D weights (win2d = a outer a, sum a = 1); pin to SGPRs.
    float wl[KW];
    {
        float c = sqrtf(window[5 * KW + 5]);
        #pragma unroll
        for (int k = 0; k < KW; ++k)
            wl[k] = rfl(window[k * KW + 5] / c);
    }

    // Zero the column-halo cells once (never written by the row pass).
    if (t < 4) {
        int buf = t >> 1, row = t & 1;
        float4 z = make_float4(0.f, 0.f, 0.f, 0.f);
        rbE[buf][row][0] = z; rbE[buf][row][1] = z;
        rbE[buf][row][130] = z; rbE[buf][row][131] = z; rbE[buf][row][132] = z;
        rbO[buf][row][0] = z; rbO[buf][row][1] = z; rbO[buf][row][2] = z;
        rbO[buf][row][131] = z; rbO[buf][row][132] = z;
    }

    const int ghbase = band * OUT_R - 5;   // global row of stream index 0

    v2f rXY[RING], rQP[RING];
    float acc = 0.f;

    // 2-deep prefetch pipeline (R5): cur = this step's pair, nxt = next.
    float cx0, cy0, cx1, cy1;
    float nx0, ny0, nx1, ny1;
    {
        int g0 = ghbase, g1 = ghbase + 1;
        cx0 = ((unsigned)g0 < (unsigned)Hd) ? p1[(g0 << 8) + t] : 0.f;
        cy0 = ((unsigned)g0 < (unsigned)Hd) ? p2[(g0 << 8) + t] : 0.f;
        cx1 = ((unsigned)g1 < (unsigned)Hd) ? p1[(g1 << 8) + t] : 0.f;
        cy1 = ((unsigned)g1 < (unsigned)Hd) ? p2[(g1 << 8) + t] : 0.f;
        int g2 = ghbase + 2, g3 = ghbase + 3;
        nx0 = ((unsigned)g2 < (unsigned)Hd) ? p1[(g2 << 8) + t] : 0.f;
        ny0 = ((unsigned)g2 < (unsigned)Hd) ? p2[(g2 << 8) + t] : 0.f;
        nx1 = ((unsigned)g3 < (unsigned)Hd) ? p1[(g3 << 8) + t] : 0.f;
        ny1 = ((unsigned)g3 < (unsigned)Hd) ? p2[(g3 << 8) + t] : 0.f;
    }

    #pragma unroll 1
    for (int ch = 0; ch < 3; ++ch) {
        #pragma unroll
        for (int jp = 0; jp < 6; ++jp) {
            const int i0 = 12 * ch + 2 * jp;        // uniform (ch runtime)
            const int s0 = (2 * jp) % RING;         // STATIC slot
            const int s1 = (2 * jp + 1) % RING;     // STATIC slot

            // ring insert rows i0, i0+1 (consume cur; out-of-range = zeros)
            {
                v2f v; v.x = cx0; v.y = cy0; rXY[s0] = v;
                v2f q; q.x = fmaf(cx0, cx0, cy0 * cy0); q.y = cx0 * cy0; rQP[s0] = q;
                v2f v2; v2.x = cx1; v2.y = cy1; rXY[s1] = v2;
                v2f q2; q2.x = fmaf(cx1, cx1, cy1 * cy1); q2.y = cx1 * cy1; rQP[s1] = q2;
            }
            // rotate pipeline, issue loads 2 steps ahead
            cx0 = nx0; cy0 = ny0; cx1 = nx1; cy1 = ny1;
            if (i0 + 4 < 36) {
                int g0 = ghbase + i0 + 4, g1 = ghbase + i0 + 5;
                nx0 = ((unsigned)g0 < (unsigned)Hd) ? p1[(g0 << 8) + t] : 0.f;
                ny0 = ((unsigned)g0 < (unsigned)Hd) ? p2[(g0 << 8) + t] : 0.f;
                nx1 = ((unsigned)g1 < (unsigned)Hd) ? p1[(g1 << 8) + t] : 0.f;
                ny1 = ((unsigned)g1 < (unsigned)Hd) ? p2[(g1 << 8) + t] : 0.f;
            }

            const int orow0 = band * OUT_R + i0 - 10;     // uniform
            if (i0 >= 10 && orow0 < Hd) {   // emit rows i0, i0+1
                __builtin_amdgcn_s_setprio(1);   // T5: favor compute-phase waves
                const int buf = jp & 1;
                v2f vAB0, vQP0, vAB1, vQP1;
                vAB0.x = vAB0.y = vQP0.x = vQP0.y = 0.f;
                vAB1.x = vAB1.y = vQP1.x = vQP1.y = 0.f;
                #pragma unroll
                for (int m = 0; m < KW; ++m) {
                    const int sa = (2 * jp + 2 + m) % RING;
                    const int sb = (2 * jp + 3 + m) % RING;
                    float w = wl[m];
                    vAB0 += w * rXY[sa];  vQP0 += w * rQP[sa];
                    vAB1 += w * rXY[sb];  vQP1 += w * rQP[sb];
                }
                const int half = t >> 1;
                if (t & 1) {
                    rbO[buf][0][half + 3] = make_float4(vAB0.x, vAB0.y, vQP0.x, vQP0.y);
                    rbO[buf][1][half + 3] = make_float4(vAB1.x, vAB1.y, vQP1.x, vQP1.y);
                } else {
                    rbE[buf][0][half + 2] = make_float4(vAB0.x, vAB0.y, vQP0.x, vQP0.y);
                    rbE[buf][1][half + 2] = make_float4(vAB1.x, vAB1.y, vQP1.x, vQP1.y);
                }
                barrier_lds_only();   // loads stay in flight

                const int r = t >> 7, cp = t & 127;   // output cols 2cp, 2cp+1
                const float4* bE = &rbE[buf][r][cp];
                const float4* bO = &rbO[buf][r][cp];
                v2f a0, q0, a1, q1;
                a0.x = a0.y = q0.x = q0.y = 0.f;
                a1.x = a1.y = q1.x = q1.y = 0.f;
                #pragma unroll
                for (int k = 0; k < 6; ++k) {
                    float4 vO = bO[k];                 // ds_read_b128
                    v2f oab; oab.x = vO.x; oab.y = vO.y;
                    v2f oqp; oqp.x = vO.z; oqp.y = vO.w;
                    a0 += wl[2 * k] * oab;  q0 += wl[2 * k] * oqp;
                    if (k >= 1) { a1 += wl[2 * k - 1] * oab;  q1 += wl[2 * k - 1] * oqp; }
                    float4 vE = bE[k];                 // ds_read_b128
                    v2f eab; eab.x = vE.x; eab.y = vE.y;
                    v2f eqp; eqp.x = vE.z; eqp.y = vE.w;
                    a1 += wl[2 * k] * eab;  q1 += wl[2 * k] * eqp;
                    if (k <= 4) { a0 += wl[2 * k + 1] * eab;  q0 += wl[2 * k + 1] * eqp; }
                }
                {
                    float mu1 = a0.x, mu2 = a0.y, sq = q0.x, sp = q0.y;
                    float mu12 = mu1 * mu2;
                    float musum = mu1 * mu1 + mu2 * mu2;
                    float num = (2.f * mu12 + C1) * (2.f * (sp - mu12) + C2);
                    float den = (musum + C1) * ((sq - musum) + C2);
                    acc += num * __builtin_amdgcn_rcpf(den);
                }
                {
                    float mu1 = a1.x, mu2 = a1.y, sq = q1.x, sp = q1.y;
                    float mu12 = mu1 * mu2;
                    float musum = mu1 * mu1 + mu2 * mu2;
                    float num = (2.f * mu12 + C1) * (2.f * (sp - mu12) + C2);
                    float den = (musum + C1) * ((sq - musum) + C2);
                    acc += num * __builtin_amdgcn_rcpf(den);
                }
                __builtin_amdgcn_s_setprio(0);   // back to default for load phase
            }
        }
    }

    // --- block reduction + fused global reduce (atomic; proven innocent R11) ---
    #pragma unroll
    for (int off = 32; off > 0; off >>= 1)
        acc += __shfl_down(acc, off, 64);
    int wave = t >> 6;
    if ((t & 63) == 0) red[wave] = acc;
    barrier_lds_only();
    if (t == 0) {
        float partial = red[0] + red[1] + red[2] + red[3];
        float v = partial * scale;                 // scale = -1/count
        if (band == 0 && plane == 0) v += 1.0f;    // out = 1 - sum/count
        atomicAdd(out, v);
    }
}

extern "C" void kernel_launch(void* const* d_in, const int* in_sizes, int n_in,
                              void* d_out, int out_size, void* d_ws, size_t ws_size,
                              hipStream_t stream) {
    const float* img1   = (const float*)d_in[0];
    const float* img2   = (const float*)d_in[1];
    const float* window = (const float*)d_in[2];
    float* out = (float*)d_out;

    const int planes = 16 * 9;                     // 144
    const int bands = (Hd + OUT_R - 1) / OUT_R;    // 10 (last band 22 rows)

    hipMemsetAsync(out, 0, sizeof(float), stream);

    const float scale = -(float)(1.0 / ((double)planes * Hd * Wd));
    dim3 grid(bands, planes);
    ssim_pair_kernel<<<grid, BLOCK, 0, stream>>>(img1, img2, window, out, scale);
}

// Round 14
// 121.751 us; speedup vs baseline: 1.0525x; 1.0525x over previous
//
#include <hip/hip_runtime.h>
#include <math.h>

#define Wd 256
#define Hd 256
#define KW 11
#define OUT_R 52              // output rows per block; stream 62 = 31 pair-steps
#define RING 12               // slot = (2*jp+c)%12, chunk-independent (12|60)
#define BLOCK 256

typedef float v2f __attribute__((ext_vector_type(2)));

__device__ __forceinline__ float rfl(float v) {
    return __int_as_float(__builtin_amdgcn_readfirstlane(__float_as_int(v)));
}

// lgkmcnt-only barrier (R2/R5): LDS handoff without draining global prefetch.
__device__ __forceinline__ void barrier_lds_only() {
    asm volatile("s_waitcnt lgkmcnt(0)\n\ts_barrier" ::: "memory");
}

// R14: R5 body, OUT_R 26 -> 52 (bands 10 -> 5, blocks 1440 -> 720).
//
// Ledger (~42us invariant): barrier flavor (R2), barrier count (R12),
// residency supply UP via smaller bands (R4: +20% blocks -> +20% time),
// prefetch depth (R5 -4%), skew (R6), step size/LDS layout (R7), bank
// conflicts (no effect), memory residency (L3==HBM), instruction packing
// (R9: slower), wave privatization (R10: much worse), atomics (R11),
// setprio (R13: -60%, starves co-resident blocks' load phases).
//
// R4's law re-read: duration scaled with BLOCK COUNT; each block pays a
// fixed cost -- 5 emit-free prologue steps with exposed load latency
// (~3.5K cyc) plus ramp/drain. The untested geometry direction: FEWER,
// LONGER bands. OUT_R=52 cuts total streamed rows/plane 360 -> 310 (-14%
// loads+inserts, emit work conserved) and halves the per-block prologue
// count. 720 blocks = 2.8/CU matches the observed ~3/CU residency.
// Slot math unchanged: stream row r -> slot r%12; step i0=60 (ch=5,jp=0)
// uses the same static slots since 60%12 == 0.
__global__ __launch_bounds__(BLOCK, 4) void ssim_pair_kernel(
    const float* __restrict__ img1, const float* __restrict__ img2,
    const float* __restrict__ window, float* __restrict__ out, float scale)
{
    __shared__ __align__(16) float4 rbE[2][2][136];
    __shared__ __align__(16) float4 rbO[2][2][136];   // 17.4 KB
    __shared__ float red[BLOCK / 64];

    const float C1 = 1e-4f, C2 = 9e-4f;
    const int t = threadIdx.x;
    const int band = blockIdx.x;     // 0..4 (band 4 partial: 48 rows)
    const int plane = blockIdx.y;    // 0..143
    const float* __restrict__ p1 = img1 + (size_t)plane * (Hd * Wd);
    const float* __restrict__ p2 = img2 + (size_t)plane * (Hd * Wd);

    // Separable 1D weights (win2d = a outer a, sum a = 1); pin to SGPRs.
    float wl[KW];
    {
        float c = sqrtf(window[5 * KW + 5]);
        #pragma unroll
        for (int k = 0; k < KW; ++k)
            wl[k] = rfl(window[k * KW + 5] / c);
    }

    // Zero the column-halo cells once (never written by the row pass).
    if (t < 4) {
        int buf = t >> 1, row = t & 1;
        float4 z = make_float4(0.f, 0.f, 0.f, 0.f);
        rbE[buf][row][0] = z; rbE[buf][row][1] = z;
        rbE[buf][row][130] = z; rbE[buf][row][131] = z; rbE[buf][row][132] = z;
        rbO[buf][row][0] = z; rbO[buf][row][1] = z; rbO[buf][row][2] = z;
        rbO[buf][row][131] = z; rbO[buf][row][132] = z;
    }

    const int ghbase = band * OUT_R - 5;   // global row of stream index 0

    v2f rXY[RING], rQP[RING];
    float acc = 0.f;

    // 2-deep prefetch pipeline (R5): cur = this step's pair, nxt = next.
    float cx0, cy0, cx1, cy1;
    float nx0, ny0, nx1, ny1;
    {
        int g0 = ghbase, g1 = ghbase + 1;
        cx0 = ((unsigned)g0 < (unsigned)Hd) ? p1[(g0 << 8) + t] : 0.f;
        cy0 = ((unsigned)g0 < (unsigned)Hd) ? p2[(g0 << 8) + t] : 0.f;
        cx1 = ((unsigned)g1 < (unsigned)Hd) ? p1[(g1 << 8) + t] : 0.f;
        cy1 = ((unsigned)g1 < (unsigned)Hd) ? p2[(g1 << 8) + t] : 0.f;
        int g2 = ghbase + 2, g3 = ghbase + 3;
        nx0 = ((unsigned)g2 < (unsigned)Hd) ? p1[(g2 << 8) + t] : 0.f;
        ny0 = ((unsigned)g2 < (unsigned)Hd) ? p2[(g2 << 8) + t] : 0.f;
        nx1 = ((unsigned)g3 < (unsigned)Hd) ? p1[(g3 << 8) + t] : 0.f;
        ny1 = ((unsigned)g3 < (unsigned)Hd) ? p2[(g3 << 8) + t] : 0.f;
    }

    #pragma unroll 1
    for (int ch = 0; ch < 6; ++ch) {       // pair-steps i0 = 0..60 (31 steps)
        #pragma unroll
        for (int jp = 0; jp < 6; ++jp) {
            const int i0 = 12 * ch + 2 * jp;        // uniform (ch runtime)
            if (i0 <= 60) {                         // ch=5: only jp=0 active
                const int s0 = (2 * jp) % RING;     // STATIC slot
                const int s1 = (2 * jp + 1) % RING; // STATIC slot

                // ring insert stream rows i0, i0+1 (consume cur)
                {
                    v2f v; v.x = cx0; v.y = cy0; rXY[s0] = v;
                    v2f q; q.x = fmaf(cx0, cx0, cy0 * cy0); q.y = cx0 * cy0; rQP[s0] = q;
                    v2f v2; v2.x = cx1; v2.y = cy1; rXY[s1] = v2;
                    v2f q2; q2.x = fmaf(cx1, cx1, cy1 * cy1); q2.y = cx1 * cy1; rQP[s1] = q2;
                }
                // rotate pipeline, issue loads 2 steps ahead
                cx0 = nx0; cy0 = ny0; cx1 = nx1; cy1 = ny1;
                if (i0 + 4 < 62) {
                    int g0 = ghbase + i0 + 4, g1 = ghbase + i0 + 5;
                    nx0 = ((unsigned)g0 < (unsigned)Hd) ? p1[(g0 << 8) + t] : 0.f;
                    ny0 = ((unsigned)g0 < (unsigned)Hd) ? p2[(g0 << 8) + t] : 0.f;
                    nx1 = ((unsigned)g1 < (unsigned)Hd) ? p1[(g1 << 8) + t] : 0.f;
                    ny1 = ((unsigned)g1 < (unsigned)Hd) ? p2[(g1 << 8) + t] : 0.f;
                }

                const int orow0 = band * OUT_R + i0 - 10;     // uniform
                if (i0 >= 10 && orow0 < Hd) {   // emit rows orow0, orow0+1
                    const int buf = jp & 1;
                    v2f vAB0, vQP0, vAB1, vQP1;
                    vAB0.x = vAB0.y = vQP0.x = vQP0.y = 0.f;
                    vAB1.x = vAB1.y = vQP1.x = vQP1.y = 0.f;
                    #pragma unroll
                    for (int m = 0; m < KW; ++m) {
                        const int sa = (2 * jp + 2 + m) % RING;
                        const int sb = (2 * jp + 3 + m) % RING;
                        float w = wl[m];
                        vAB0 += w * rXY[sa];  vQP0 += w * rQP[sa];
                        vAB1 += w * rXY[sb];  vQP1 += w * rQP[sb];
                    }
                    const int half = t >> 1;
                    if (t & 1) {
                        rbO[buf][0][half + 3] = make_float4(vAB0.x, vAB0.y, vQP0.x, vQP0.y);
                        rbO[buf][1][half + 3] = make_float4(vAB1.x, vAB1.y, vQP1.x, vQP1.y);
                    } else {
                        rbE[buf][0][half + 2] = make_float4(vAB0.x, vAB0.y, vQP0.x, vQP0.y);
                        rbE[buf][1][half + 2] = make_float4(vAB1.x, vAB1.y, vQP1.x, vQP1.y);
                    }
                    barrier_lds_only();   // loads stay in flight

                    const int r = t >> 7, cp = t & 127;   // output cols 2cp, 2cp+1
                    const float4* bE = &rbE[buf][r][cp];
                    const float4* bO = &rbO[buf][r][cp];
                    v2f a0, q0, a1, q1;
                    a0.x = a0.y = q0.x = q0.y = 0.f;
                    a1.x = a1.y = q1.x = q1.y = 0.f;
                    #pragma unroll
                    for (int k = 0; k < 6; ++k) {
                        float4 vO = bO[k];                 // ds_read_b128
                        v2f oab; oab.x = vO.x; oab.y = vO.y;
                        v2f oqp; oqp.x = vO.z; oqp.y = vO.w;
                        a0 += wl[2 * k] * oab;  q0 += wl[2 * k] * oqp;
                        if (k >= 1) { a1 += wl[2 * k - 1] * oab;  q1 += wl[2 * k - 1] * oqp; }
                        float4 vE = bE[k];                 // ds_read_b128
                        v2f eab; eab.x = vE.x; eab.y = vE.y;
                        v2f eqp; eqp.x = vE.z; eqp.y = vE.w;
                        a1 += wl[2 * k] * eab;  q1 += wl[2 * k] * eqp;
                        if (k <= 4) { a0 += wl[2 * k + 1] * eab;  q0 += wl[2 * k + 1] * eqp; }
                    }
                    {
                        float mu1 = a0.x, mu2 = a0.y, sq = q0.x, sp = q0.y;
                        float mu12 = mu1 * mu2;
                        float musum = mu1 * mu1 + mu2 * mu2;
                        float num = (2.f * mu12 + C1) * (2.f * (sp - mu12) + C2);
                        float den = (musum + C1) * ((sq - musum) + C2);
                        acc += num * __builtin_amdgcn_rcpf(den);
                    }
                    {
                        float mu1 = a1.x, mu2 = a1.y, sq = q1.x, sp = q1.y;
                        float mu12 = mu1 * mu2;
                        float musum = mu1 * mu1 + mu2 * mu2;
                        float num = (2.f * mu12 + C1) * (2.f * (sp - mu12) + C2);
                        float den = (musum + C1) * ((sq - musum) + C2);
                        acc += num * __builtin_amdgcn_rcpf(den);
                    }
                }
            }
        }
    }

    // --- block reduction + fused global reduce (atomic; proven innocent R11) ---
    #pragma unroll
    for (int off = 32; off > 0; off >>= 1)
        acc += __shfl_down(acc, off, 64);
    int wave = t >> 6;
    if ((t & 63) == 0) red[wave] = acc;
    barrier_lds_only();
    if (t == 0) {
        float partial = red[0] + red[1] + red[2] + red[3];
        float v = partial * scale;                 // scale = -1/count
        if (band == 0 && plane == 0) v += 1.0f;    // out = 1 - sum/count
        atomicAdd(out, v);
    }
}

extern "C" void kernel_launch(void* const* d_in, const int* in_sizes, int n_in,
                              void* d_out, int out_size, void* d_ws, size_t ws_size,
                              hipStream_t stream) {
    const float* img1   = (const float*)d_in[0];
    const float* img2   = (const float*)d_in[1];
    const float* window = (const float*)d_in[2];
    float* out = (float*)d_out;

    const int planes = 16 * 9;                     // 144
    const int bands = (Hd + OUT_R - 1) / OUT_R;    // 5 (last band 48 rows)

    hipMemsetAsync(out, 0, sizeof(float), stream);

    const float scale = -(float)(1.0 / ((double)planes * Hd * Wd));
    dim3 grid(bands, planes);
    ssim_pair_kernel<<<grid, BLOCK, 0, stream>>>(img1, img2, window, out, scale);
}